// Round 6
// baseline (410.385 us; speedup 1.0000x reference)
//
#include <hip/hip_runtime.h>
#include <hip/hip_bf16.h>
#include <math.h>

#define NN 10000
#define NE 160000
#define HD 128
#define NL 4
#define NG 64

typedef __attribute__((ext_vector_type(8))) short bf16x8;
typedef __attribute__((ext_vector_type(4))) short bf16x4;
typedef __attribute__((ext_vector_type(4))) float f32x4;

// fp32 -> bf16 (round to nearest even), finite inputs
static __device__ __forceinline__ short f2bf(float f) {
    unsigned u = __float_as_uint(f);
    unsigned r = (u + 0x7FFFu + ((u >> 16) & 1u)) >> 16;
    return (short)r;
}
static __device__ __forceinline__ float bf2f(short s) {
    return __uint_as_float(((unsigned)(unsigned short)s) << 16);
}

__global__ void embed_kernel(const int* __restrict__ x, const float* __restrict__ atom_emb,
                             float* __restrict__ h, float* __restrict__ deg,
                             int* __restrict__ cursor) {
    int idx = blockIdx.x * 256 + threadIdx.x;
    if (idx < NN) { deg[idx] = 0.f; cursor[idx] = 0; }
    if (idx < NN * HD) {
        int n = idx >> 7, f = idx & 127;
        h[idx] = atom_emb[x[n] * HD + f];
    }
}

__global__ void deg_kernel(const int* __restrict__ col, float* __restrict__ deg) {
    int e = blockIdx.x * 256 + threadIdx.x;
    if (e < NE) atomicAdd(&deg[col[e]], 1.f);
}

// One-pass parallel exclusive scan (1024 thr x 10 elems, 20 barriers) + amp/att factors.
__global__ __launch_bounds__(1024) void scan_facs_kernel(const float* __restrict__ deg,
                                                         int* __restrict__ offsets,
                                                         float* __restrict__ amp,
                                                         float* __restrict__ att) {
    __shared__ int s[1024];
    int t = threadIdx.x;
    int base = t * 10;
    int v[10];
    int lsum = 0;
    #pragma unroll
    for (int i = 0; i < 10; ++i) {
        int idx = base + i;
        int d = (idx < NN) ? (int)deg[idx] : 0;
        v[i] = d;
        lsum += d;
        if (idx < NN) {
            float logD = logf((float)d + 1.f);
            amp[idx] = logD;                       // / AVG_D_LOG (=1.0)
            att[idx] = 1.f / fmaxf(logD, 1e-8f);   // AVG_D_LOG / max(logD, eps)
        }
    }
    s[t] = lsum;
    __syncthreads();
    for (int off = 1; off < 1024; off <<= 1) {
        int x2 = (t >= off) ? s[t - off] : 0;
        __syncthreads();
        s[t] += x2;
        __syncthreads();
    }
    int run = s[t] - lsum;   // exclusive prefix for this thread's chunk
    #pragma unroll
    for (int i = 0; i < 10; ++i) {
        int idx = base + i;
        if (idx < NN) offsets[idx] = run;
        run += v[i];
    }
    if (t == 1023) offsets[NN] = run;   // = NE
}

__global__ void scatter_kernel(const int* __restrict__ row, const int* __restrict__ col,
                               const int* __restrict__ ea, const int* __restrict__ offsets,
                               int* __restrict__ cursor, int* __restrict__ perm) {
    int e = blockIdx.x * 256 + threadIdx.x;
    if (e < NE) {
        int c = col[e];
        int pos = offsets[c] + atomicAdd(&cursor[c], 1);
        perm[pos] = row[e] | (ea[e] << 14);   // row < 16384, ea < 5
    }
}

// Fused: blocks 0..19 compute btab (bond_emb @ pre_W[256:384] + pre_b);
// remaining blocks convert weights into bf16 K-blocked layouts:
//   pre_Wt[l][kblk<4][j<256][k<32]: j<128 -> pre_W[l][kblk*32+k][j], else pre_W[l][128+kblk*32+k][j-128]
//   post_Wt[l][kblk<40][j<128][k<32]: post_W[l][kblk*32+k][j]
__global__ __launch_bounds__(256) void convw_bondtab_kernel(
    const float* __restrict__ bond_emb,
    const float* __restrict__ pre_W, const float* __restrict__ pre_b,
    const float* __restrict__ post_W,
    float* __restrict__ btab, short* __restrict__ pre_Wt, short* __restrict__ post_Wt) {
    int b = blockIdx.x;
    if (b < 20) {
        if (threadIdx.x < 128) {
            int l = b / 5, bb = b % 5;
            int f = threadIdx.x;
            const float* W2 = pre_W + (size_t)l * 384 * HD + 256 * HD;
            const float* eb = bond_emb + bb * HD;
            float acc = pre_b[l * HD + f];
            for (int k = 0; k < HD; ++k) acc = fmaf(eb[k], W2[k * HD + f], acc);
            btab[(l * 5 + bb) * HD + f] = acc;
        }
        return;
    }
    int idx = (b - 20) * 256 + threadIdx.x;
    if (idx < NL * 4 * 256 * 32) {      // 131072
        int l = idx >> 15;
        int r = idx & 32767;
        int kblk = r >> 13;
        int rr = r & 8191;
        int j = rr >> 5, k = rr & 31;
        const float* Wl = pre_W + (size_t)l * 384 * HD;
        float v = (j < 128) ? Wl[(kblk * 32 + k) * HD + j]
                            : Wl[(128 + kblk * 32 + k) * HD + (j - 128)];
        pre_Wt[idx] = f2bf(v);
    }
    if (idx < NL * 40 * 128 * 32) {     // 655360
        int l = idx / 163840;
        int r = idx % 163840;
        int kblk = r >> 12;
        int rr = r & 4095;
        int j = rr >> 5, k = rr & 31;
        post_Wt[idx] = f2bf(post_W[(size_t)l * 163840 + (size_t)(kblk * 32 + k) * HD + j]);
    }
}

// hw0[n] = h[n] @ W0 (bf16), hw1[n] = h[n] @ W1 (fp32). One block = 32 nodes x 256 cols.
// 4 waves split output 2M x 2colhalf; shared A/B staging; full K per wave. Coalesced blocked B.
__global__ __launch_bounds__(256) void pre_gemm_mfma(const float* __restrict__ h,
                                                     const short* __restrict__ Wt, // [4][256][32]
                                                     short* __restrict__ hw0,
                                                     float* __restrict__ hw1) {
    __shared__ short As[32 * 40];
    __shared__ short Bs[256 * 40];
    int t = threadIdx.x;
    int nb = blockIdx.x * 32;
    int wave = t >> 6, lane = t & 63;
    int mhalf = wave & 1, jhalf = wave >> 1;
    int lx = lane & 15, kb = lane >> 4;
    int frow = mhalf * 16 + lx;
    int arow = t >> 3, seg = t & 7;
    int an = nb + arow;
    bool aval = an < NN;
    f32x4 acc[8];
    #pragma unroll
    for (int j = 0; j < 8; ++j) acc[j] = (f32x4){0.f, 0.f, 0.f, 0.f};

    for (int kblk = 0; kblk < 4; ++kblk) {
        __syncthreads();
        {   // A: 32 rows x 32 k, fp32 -> bf16, 8 thr/row x 4 floats
            float4 x = make_float4(0.f, 0.f, 0.f, 0.f);
            if (aval) x = *(const float4*)(h + (size_t)an * HD + kblk * 32 + seg * 4);
            bf16x4 pk;
            pk[0] = f2bf(x.x); pk[1] = f2bf(x.y); pk[2] = f2bf(x.z); pk[3] = f2bf(x.w);
            *(bf16x4*)&As[arow * 40 + seg * 4] = pk;
        }
        {   // B: thread t loads row t (32 shorts contiguous in blocked layout)
            const short* src = Wt + (size_t)kblk * (256 * 32) + (size_t)t * 32;
            #pragma unroll
            for (int q = 0; q < 4; ++q)
                *(bf16x8*)&Bs[t * 40 + q * 8] = *(const bf16x8*)(src + q * 8);
        }
        __syncthreads();
        bf16x8 a = *(const bf16x8*)&As[frow * 40 + kb * 8];
        #pragma unroll
        for (int jj = 0; jj < 8; ++jj) {
            int j = jhalf * 128 + jj * 16 + lx;
            bf16x8 bfr = *(const bf16x8*)&Bs[j * 40 + kb * 8];
            acc[jj] = __builtin_amdgcn_mfma_f32_16x16x32_bf16(a, bfr, acc[jj], 0, 0, 0);
        }
    }
    #pragma unroll
    for (int jj = 0; jj < 8; ++jj) {
        int cl = jj * 16 + lx;
        #pragma unroll
        for (int r_ = 0; r_ < 4; ++r_) {
            int n2 = nb + mhalf * 16 + kb * 4 + r_;
            if (n2 < NN) {
                if (jhalf == 0) hw0[(size_t)n2 * HD + cl] = f2bf(acc[jj][r_]);
                else            hw1[(size_t)n2 * HD + cl] = acc[jj][r_];
            }
        }
    }
}

// per-node CSR aggregation: bf16 gathers + 4-edge unroll; no atomics.
// agg[n] = [mean(128) | sum(128) | max(128)]
__global__ __launch_bounds__(256) void agg_kernel(const short* __restrict__ hw0,
                                                  const float* __restrict__ hw1,
                                                  const float* __restrict__ btab,
                                                  const int* __restrict__ offsets,
                                                  const int* __restrict__ perm,
                                                  float* __restrict__ agg) {
    int t = threadIdx.x;
    int n = blockIdx.x * 8 + (t >> 5);
    int f = (t & 31) * 4;
    if (n >= NN) return;
    int s0 = offsets[n];
    int d = offsets[n + 1] - s0;
    f32x4 sum = {0.f, 0.f, 0.f, 0.f};
    f32x4 mx = {-INFINITY, -INFINITY, -INFINITY, -INFINITY};
    int i = 0;
    for (; i + 4 <= d; i += 4) {
        int p0 = perm[s0 + i], p1 = perm[s0 + i + 1];
        int p2 = perm[s0 + i + 2], p3 = perm[s0 + i + 3];
        bf16x4 a0 = *(const bf16x4*)(hw0 + (size_t)(p0 & 16383) * HD + f);
        bf16x4 a1 = *(const bf16x4*)(hw0 + (size_t)(p1 & 16383) * HD + f);
        bf16x4 a2 = *(const bf16x4*)(hw0 + (size_t)(p2 & 16383) * HD + f);
        bf16x4 a3 = *(const bf16x4*)(hw0 + (size_t)(p3 & 16383) * HD + f);
        f32x4 b0 = *(const f32x4*)(btab + (p0 >> 14) * HD + f);
        f32x4 b1 = *(const f32x4*)(btab + (p1 >> 14) * HD + f);
        f32x4 b2 = *(const f32x4*)(btab + (p2 >> 14) * HD + f);
        f32x4 b3 = *(const f32x4*)(btab + (p3 >> 14) * HD + f);
        f32x4 v0, v1, v2, v3;
        #pragma unroll
        for (int q = 0; q < 4; ++q) {
            v0[q] = bf2f(a0[q]) + b0[q];
            v1[q] = bf2f(a1[q]) + b1[q];
            v2[q] = bf2f(a2[q]) + b2[q];
            v3[q] = bf2f(a3[q]) + b3[q];
        }
        sum += v0 + v1 + v2 + v3;
        #pragma unroll
        for (int q = 0; q < 4; ++q)
            mx[q] = fmaxf(fmaxf(fmaxf(mx[q], v0[q]), fmaxf(v1[q], v2[q])), v3[q]);
    }
    for (; i < d; ++i) {
        int p0 = perm[s0 + i];
        bf16x4 a0 = *(const bf16x4*)(hw0 + (size_t)(p0 & 16383) * HD + f);
        f32x4 b0 = *(const f32x4*)(btab + (p0 >> 14) * HD + f);
        f32x4 v0;
        #pragma unroll
        for (int q = 0; q < 4; ++q) v0[q] = bf2f(a0[q]) + b0[q];
        sum += v0;
        #pragma unroll
        for (int q = 0; q < 4; ++q) mx[q] = fmaxf(mx[q], v0[q]);
    }
    f32x4 c = *(const f32x4*)(hw1 + (size_t)n * HD + f);
    f32x4 mean, so, mo;
    if (d > 0) {
        float df = (float)d, di = 1.f / df;
        so = sum + df * c;
        mean = sum * di + c;
        mo = mx + c;
    } else {
        so = (f32x4){0.f,0.f,0.f,0.f}; mean = so; mo = so;
    }
    *(f32x4*)(agg + (size_t)n * 384 + f) = mean;
    *(f32x4*)(agg + (size_t)n * 384 + 128 + f) = so;
    *(f32x4*)(agg + (size_t)n * 384 + 256 + f) = mo;
}

// (N,1280)@(1280,128), hcat on the fly, bias+residual fused. One block = 32 nodes.
// 4 waves split output 2M x 2colhalf, shared staging, full K. Coalesced blocked B.
// hcat regions (128 wide): r<9: agg[r%3] * {1,amp,att}[r/3]; r==9: h_in.
__global__ __launch_bounds__(256) void node_gemm_mfma(
    const float* __restrict__ agg, const float* __restrict__ hin,
    const float* __restrict__ amp, const float* __restrict__ att,
    const short* __restrict__ Wt /* [40][128][32] */, const float* __restrict__ bias,
    float* __restrict__ hout) {
    __shared__ short As[32 * 40];
    __shared__ short Bs[128 * 40];
    int t = threadIdx.x;
    int nb = blockIdx.x * 32;
    int wave = t >> 6, lane = t & 63;
    int mhalf = wave & 1, jhalf = wave >> 1;
    int lx = lane & 15, kb = lane >> 4;
    int frow = mhalf * 16 + lx;
    int arow = t >> 3, seg = t & 7;
    int an = nb + arow;
    bool aval = an < NN;
    float f_amp = 0.f, f_att = 0.f;
    if (aval) { f_amp = amp[an]; f_att = att[an]; }
    f32x4 acc[4];
    #pragma unroll
    for (int j = 0; j < 4; ++j) acc[j] = (f32x4){0.f, 0.f, 0.f, 0.f};

    for (int ks = 0; ks < 40; ++ks) {
        __syncthreads();
        {   // A: 32 rows x 32 k of hcat, fp32 -> bf16, 8 thr/row x 4 floats
            int r = ks >> 2;
            int kbase = (ks & 3) * 32 + seg * 4;
            float4 x = make_float4(0.f, 0.f, 0.f, 0.f);
            float fac = 1.f;
            if (aval) {
                if (r < 9) {
                    int ag = r % 3, fi = r / 3;
                    fac = (fi == 0) ? 1.f : ((fi == 1) ? f_amp : f_att);
                    x = *(const float4*)(agg + (size_t)an * 384 + ag * 128 + kbase);
                } else {
                    x = *(const float4*)(hin + (size_t)an * HD + kbase);
                }
            }
            bf16x4 pk;
            pk[0] = f2bf(x.x * fac); pk[1] = f2bf(x.y * fac);
            pk[2] = f2bf(x.z * fac); pk[3] = f2bf(x.w * fac);
            *(bf16x4*)&As[arow * 40 + seg * 4] = pk;
        }
        {   // B: 128 rows x 32 shorts; 2 thr/row x 16 shorts, contiguous blocked layout
            int brow = t >> 1, bh = t & 1;
            const short* src = Wt + (size_t)ks * 4096 + (size_t)brow * 32 + bh * 16;
            *(bf16x8*)&Bs[brow * 40 + bh * 16] = *(const bf16x8*)src;
            *(bf16x8*)&Bs[brow * 40 + bh * 16 + 8] = *(const bf16x8*)(src + 8);
        }
        __syncthreads();
        bf16x8 a = *(const bf16x8*)&As[frow * 40 + kb * 8];
        #pragma unroll
        for (int jj = 0; jj < 4; ++jj) {
            int j = jhalf * 64 + jj * 16 + lx;
            bf16x8 bfr = *(const bf16x8*)&Bs[j * 40 + kb * 8];
            acc[jj] = __builtin_amdgcn_mfma_f32_16x16x32_bf16(a, bfr, acc[jj], 0, 0, 0);
        }
    }
    #pragma unroll
    for (int jj = 0; jj < 4; ++jj) {
        int c = jhalf * 64 + jj * 16 + lx;
        float bc = bias[c];
        #pragma unroll
        for (int r_ = 0; r_ < 4; ++r_) {
            int n2 = nb + mhalf * 16 + kb * 4 + r_;
            if (n2 < NN) {
                size_t off = (size_t)n2 * HD + c;
                hout[off] = acc[jj][r_] + bc + hin[off];
            }
        }
    }
}

// Fused deterministic graph pooling + output MLP. One block per graph (batch sorted).
__global__ __launch_bounds__(256) void pool_out_kernel(
    const float* __restrict__ h, const int* __restrict__ batch,
    const float* __restrict__ W1, const float* __restrict__ b1,
    const float* __restrict__ W2, const float* __restrict__ b2,
    float* __restrict__ out)
{
    __shared__ float rs[384];
    __shared__ float red[256];
    __shared__ float s2[128], m2[128];
    int g = blockIdx.x, t = threadIdx.x;
    int lo = 0, hi = NN;
    while (lo < hi) { int mid = (lo + hi) >> 1; if (batch[mid] < g) lo = mid + 1; else hi = mid; }
    int lo2 = lo, hi2 = NN;
    while (lo2 < hi2) { int mid = (lo2 + hi2) >> 1; if (batch[mid] < g + 1) lo2 = mid + 1; else hi2 = mid; }
    int cnt = lo2 - lo;
    int f = t & 127, grp = t >> 7;
    float sum = 0.f, mx = -INFINITY;
    for (int n = lo + grp; n < lo2; n += 2) {
        float v = h[(size_t)n * HD + f];
        sum += v; mx = fmaxf(mx, v);
    }
    if (grp == 1) { s2[f] = sum; m2[f] = mx; }
    __syncthreads();
    if (grp == 0) {
        sum += s2[f]; mx = fmaxf(mx, m2[f]);
        float mean = (cnt > 0) ? sum / (float)cnt : 0.f;
        float so = (cnt > 0) ? sum : 0.f;
        float mo = (cnt > 0) ? mx : 0.f;
        if (isnan(mean) || isinf(mean)) mean = 0.f;
        if (isnan(so) || isinf(so)) so = 0.f;
        if (isnan(mo) || isinf(mo)) mo = 0.f;
        rs[f] = mean; rs[128 + f] = so; rs[256 + f] = mo;
    }
    __syncthreads();
    {
        int j = t & 127, kh = t >> 7;
        float acc = 0.f;
        for (int k = kh * 192; k < kh * 192 + 192; ++k)
            acc = fmaf(rs[k], W1[k * HD + j], acc);
        red[t] = acc;
    }
    __syncthreads();
    if (t < 128) {
        float v = fmaxf(red[t] + red[128 + t] + b1[t], 0.f);
        red[t] = v * W2[t];
    }
    __syncthreads();
    for (int s = 64; s > 0; s >>= 1) {
        if (t < s) red[t] += red[t + s];
        __syncthreads();
    }
    if (t == 0) {
        float o = red[0] + b2[0];
        if (isnan(o) || isinf(o)) o = 0.f;
        out[g] = o;
    }
}

extern "C" void kernel_launch(void* const* d_in, const int* in_sizes, int n_in,
                              void* d_out, int out_size, void* d_ws, size_t ws_size,
                              hipStream_t stream)
{
    const int* x          = (const int*)d_in[0];
    const int* ei         = (const int*)d_in[1];
    const int* ea         = (const int*)d_in[2];
    const int* batch      = (const int*)d_in[3];
    const float* atom_emb = (const float*)d_in[4];
    const float* bond_emb = (const float*)d_in[5];
    const float* pre_W    = (const float*)d_in[6];
    const float* pre_b    = (const float*)d_in[7];
    const float* post_W   = (const float*)d_in[8];
    const float* post_b   = (const float*)d_in[9];
    const float* out_W1   = (const float*)d_in[10];
    const float* out_b1   = (const float*)d_in[11];
    const float* out_W2   = (const float*)d_in[12];
    const float* out_b2   = (const float*)d_in[13];
    float* out = (float*)d_out;
    const int* row = ei;
    const int* col = ei + NE;

    char* p = (char*)d_ws;
    auto alloc = [&](size_t bytes) { char* r = p; p += (bytes + 255) & ~(size_t)255; return r; };
    float*    deg     = (float*)alloc((size_t)NN * 4);
    float*    amp     = (float*)alloc((size_t)NN * 4);
    float*    att     = (float*)alloc((size_t)NN * 4);
    int*      offsets = (int*)alloc((size_t)(NN + 1) * 4);
    int*      cursor  = (int*)alloc((size_t)NN * 4);
    int*      perm    = (int*)alloc((size_t)NE * 4);
    float*    hA      = (float*)alloc((size_t)NN * HD * 4);
    float*    hB      = (float*)alloc((size_t)NN * HD * 4);
    short*    hw0     = (short*)alloc((size_t)NN * HD * 2);
    float*    hw1     = (float*)alloc((size_t)NN * HD * 4);
    float*    agg     = (float*)alloc((size_t)NN * 384 * 4);
    float*    btab    = (float*)alloc((size_t)NL * 5 * HD * 4);
    short*    pre_Wt  = (short*)alloc((size_t)NL * 4 * 256 * 32 * 2);
    short*    post_Wt = (short*)alloc((size_t)NL * 40 * 128 * 32 * 2);

    embed_kernel<<<(NN * HD) / 256, 256, 0, stream>>>(x, atom_emb, hA, deg, cursor);
    deg_kernel<<<(NE + 255) / 256, 256, 0, stream>>>(col, deg);
    scan_facs_kernel<<<1, 1024, 0, stream>>>(deg, offsets, amp, att);
    scatter_kernel<<<(NE + 255) / 256, 256, 0, stream>>>(row, col, ea, offsets, cursor, perm);
    convw_bondtab_kernel<<<20 + (NL * 40 * 128 * 32 + 255) / 256, 256, 0, stream>>>(
        bond_emb, pre_W, pre_b, post_W, btab, pre_Wt, post_Wt);

    float* curH = hA;
    float* nxtH = hB;
    for (int l = 0; l < NL; ++l) {
        pre_gemm_mfma<<<(NN + 31) / 32, 256, 0, stream>>>(
            curH, pre_Wt + (size_t)l * 4 * 256 * 32, hw0, hw1);
        agg_kernel<<<(NN + 7) / 8, 256, 0, stream>>>(hw0, hw1, btab + (size_t)l * 5 * HD,
                                                     offsets, perm, agg);
        node_gemm_mfma<<<(NN + 31) / 32, 256, 0, stream>>>(
            agg, curH, amp, att, post_Wt + (size_t)l * 40 * 128 * 32,
            post_b + (size_t)l * HD, nxtH);
        float* tmp = curH; curH = nxtH; nxtH = tmp;
    }

    pool_out_kernel<<<NG, 256, 0, stream>>>(curH, batch, out_W1, out_b1, out_W2, out_b2, out);
}

// Round 8
// 397.502 us; speedup vs baseline: 1.0324x; 1.0324x over previous
//
#include <hip/hip_runtime.h>
#include <hip/hip_bf16.h>
#include <math.h>

#define NN 10000
#define NE 160000
#define HD 128
#define NL 4
#define NG 64

typedef __attribute__((ext_vector_type(8))) short bf16x8;
typedef __attribute__((ext_vector_type(4))) short bf16x4;
typedef __attribute__((ext_vector_type(4))) float f32x4;

// fp32 -> bf16 (round to nearest even), finite inputs
static __device__ __forceinline__ short f2bf(float f) {
    unsigned u = __float_as_uint(f);
    unsigned r = (u + 0x7FFFu + ((u >> 16) & 1u)) >> 16;
    return (short)r;
}
static __device__ __forceinline__ float bf2f(short s) {
    return __uint_as_float(((unsigned)(unsigned short)s) << 16);
}

__global__ void embed_kernel(const int* __restrict__ x, const float* __restrict__ atom_emb,
                             float* __restrict__ h, float* __restrict__ deg,
                             int* __restrict__ cursor) {
    int idx = blockIdx.x * 256 + threadIdx.x;
    if (idx < NN) { deg[idx] = 0.f; cursor[idx] = 0; }
    if (idx < NN * HD) {
        int n = idx >> 7, f = idx & 127;
        h[idx] = atom_emb[x[n] * HD + f];
    }
}

__global__ void deg_kernel(const int* __restrict__ col, float* __restrict__ deg) {
    int e = blockIdx.x * 256 + threadIdx.x;
    if (e < NE) atomicAdd(&deg[col[e]], 1.f);
}

// One-pass parallel exclusive scan (1024 thr x 10 elems) + amp/att factors.
__global__ __launch_bounds__(1024) void scan_facs_kernel(const float* __restrict__ deg,
                                                         int* __restrict__ offsets,
                                                         float* __restrict__ amp,
                                                         float* __restrict__ att) {
    __shared__ int s[1024];
    int t = threadIdx.x;
    int base = t * 10;
    int v[10];
    int lsum = 0;
    #pragma unroll
    for (int i = 0; i < 10; ++i) {
        int idx = base + i;
        int d = (idx < NN) ? (int)deg[idx] : 0;
        v[i] = d;
        lsum += d;
        if (idx < NN) {
            float logD = logf((float)d + 1.f);
            amp[idx] = logD;                       // / AVG_D_LOG (=1.0)
            att[idx] = 1.f / fmaxf(logD, 1e-8f);   // AVG_D_LOG / max(logD, eps)
        }
    }
    s[t] = lsum;
    __syncthreads();
    for (int off = 1; off < 1024; off <<= 1) {
        int x2 = (t >= off) ? s[t - off] : 0;
        __syncthreads();
        s[t] += x2;
        __syncthreads();
    }
    int run = s[t] - lsum;
    #pragma unroll
    for (int i = 0; i < 10; ++i) {
        int idx = base + i;
        if (idx < NN) offsets[idx] = run;
        run += v[i];
    }
    if (t == 1023) offsets[NN] = run;   // = NE
}

__global__ void scatter_kernel(const int* __restrict__ row, const int* __restrict__ col,
                               const int* __restrict__ ea, const int* __restrict__ offsets,
                               int* __restrict__ cursor, int* __restrict__ perm) {
    int e = blockIdx.x * 256 + threadIdx.x;
    if (e < NE) {
        int c = col[e];
        int pos = offsets[c] + atomicAdd(&cursor[c], 1);
        perm[pos] = row[e] | (ea[e] << 14);   // row < 16384, ea < 5
    }
}

// Fused: blocks 0..19 compute btab; remaining blocks convert weights to bf16 K-blocked:
//   pre_Wt[l][kblk<4][j<256][k<32], post_Wt[l][kblk<40][j<128][k<32]
__global__ __launch_bounds__(256) void convw_bondtab_kernel(
    const float* __restrict__ bond_emb,
    const float* __restrict__ pre_W, const float* __restrict__ pre_b,
    const float* __restrict__ post_W,
    float* __restrict__ btab, short* __restrict__ pre_Wt, short* __restrict__ post_Wt) {
    int b = blockIdx.x;
    if (b < 20) {
        if (threadIdx.x < 128) {
            int l = b / 5, bb = b % 5;
            int f = threadIdx.x;
            const float* W2 = pre_W + (size_t)l * 384 * HD + 256 * HD;
            const float* eb = bond_emb + bb * HD;
            float acc = pre_b[l * HD + f];
            for (int k = 0; k < HD; ++k) acc = fmaf(eb[k], W2[k * HD + f], acc);
            btab[(l * 5 + bb) * HD + f] = acc;
        }
        return;
    }
    int idx = (b - 20) * 256 + threadIdx.x;
    if (idx < NL * 4 * 256 * 32) {      // 131072
        int l = idx >> 15;
        int r = idx & 32767;
        int kblk = r >> 13;
        int rr = r & 8191;
        int j = rr >> 5, k = rr & 31;
        const float* Wl = pre_W + (size_t)l * 384 * HD;
        float v = (j < 128) ? Wl[(kblk * 32 + k) * HD + j]
                            : Wl[(128 + kblk * 32 + k) * HD + (j - 128)];
        pre_Wt[idx] = f2bf(v);
    }
    if (idx < NL * 40 * 128 * 32) {     // 655360
        int l = idx / 163840;
        int r = idx % 163840;
        int kblk = r >> 12;
        int rr = r & 4095;
        int j = rr >> 5, k = rr & 31;
        post_Wt[idx] = f2bf(post_W[(size_t)l * 163840 + (size_t)(kblk * 32 + k) * HD + j]);
    }
}

// hw0[n] = h[n] @ W0 (bf16), hw1[n] = h[n] @ W1 (fp32).
// 32 nodes/block, 128 thr (2 waves = M-halves), grid.y = col-half. Blocked coalesced B.
__global__ __launch_bounds__(128) void pre_gemm_mfma(const float* __restrict__ h,
                                                     const short* __restrict__ Wt, // [4][256][32]
                                                     short* __restrict__ hw0,
                                                     float* __restrict__ hw1) {
    __shared__ short As[32 * 40];
    __shared__ short Bs[128 * 40];
    int t = threadIdx.x;
    int nb = blockIdx.x * 32;
    int half = blockIdx.y;
    int wave = t >> 6, lane = t & 63;
    int lx = lane & 15, kb = lane >> 4;
    int frow = wave * 16 + lx;
    int arow = t >> 2, akl = (t & 3) * 8;
    int an = nb + arow;
    bool aval = an < NN;
    f32x4 acc[8];
    #pragma unroll
    for (int j = 0; j < 8; ++j) acc[j] = (f32x4){0.f, 0.f, 0.f, 0.f};

    for (int kblk = 0; kblk < 4; ++kblk) {
        __syncthreads();
        {   // A: 32 rows x 32 k, fp32 -> bf16 (4 thr/row x 8 floats)
            float v[8];
            if (aval) {
                const float* src = h + (size_t)an * HD + kblk * 32 + akl;
                float4 x0 = *(const float4*)src, x1 = *(const float4*)(src + 4);
                v[0]=x0.x; v[1]=x0.y; v[2]=x0.z; v[3]=x0.w;
                v[4]=x1.x; v[5]=x1.y; v[6]=x1.z; v[7]=x1.w;
            } else {
                #pragma unroll
                for (int q = 0; q < 8; ++q) v[q] = 0.f;
            }
            bf16x8 pk;
            #pragma unroll
            for (int q = 0; q < 8; ++q) pk[q] = f2bf(v[q]);
            *(bf16x8*)&As[arow * 40 + akl] = pk;
        }
        {   // B: row j = half*128 + t, 32 shorts contiguous (blocked layout)
            const short* src = Wt + (size_t)kblk * (256 * 32) + (size_t)(half * 128 + t) * 32;
            #pragma unroll
            for (int q = 0; q < 4; ++q)
                *(bf16x8*)&Bs[t * 40 + q * 8] = *(const bf16x8*)(src + q * 8);
        }
        __syncthreads();
        bf16x8 a = *(const bf16x8*)&As[frow * 40 + kb * 8];
        #pragma unroll
        for (int jj = 0; jj < 8; ++jj) {
            bf16x8 bfr = *(const bf16x8*)&Bs[(jj * 16 + lx) * 40 + kb * 8];
            acc[jj] = __builtin_amdgcn_mfma_f32_16x16x32_bf16(a, bfr, acc[jj], 0, 0, 0);
        }
    }
    #pragma unroll
    for (int jj = 0; jj < 8; ++jj) {
        int cl = jj * 16 + lx;
        #pragma unroll
        for (int r_ = 0; r_ < 4; ++r_) {
            int n2 = nb + wave * 16 + kb * 4 + r_;
            if (n2 < NN) {
                if (half == 0) hw0[(size_t)n2 * HD + cl] = f2bf(acc[jj][r_]);
                else           hw1[(size_t)n2 * HD + cl] = acc[jj][r_];
            }
        }
    }
}

// FUSED per-layer kernel: Phase A = CSR aggregation of this block's 32 nodes into LDS;
// Phase B = (32,1280)@(1280,128) MFMA GEMM with hcat built from LDS agg; bias+residual fused.
// hcat regions (128 wide): r<9: agg[r%3] * {1,amp,att}[r/3]; r==9: h_in.
__global__ __launch_bounds__(256) void agg_node_gemm_mfma(
    const short* __restrict__ hw0, const float* __restrict__ hw1,
    const float* __restrict__ btab,
    const int* __restrict__ offsets, const int* __restrict__ perm,
    const float* __restrict__ hin,
    const float* __restrict__ amp, const float* __restrict__ att,
    const short* __restrict__ Wt /* [40][128][32] */, const float* __restrict__ bias,
    float* __restrict__ hout) {
    __shared__ float agg_s[32][388];   // [0:128] mean | [128:256] sum | [256:384] max; +4 pad
    __shared__ short As[32 * 40];
    __shared__ short Bs[128 * 40];
    int t = threadIdx.x;
    int nb = blockIdx.x * 32;

    // ---- Phase A: aggregate 32 nodes; 16 lanes/node x 8 feats, 2 passes ----
    #pragma unroll
    for (int pass = 0; pass < 2; ++pass) {
        int nl = pass * 16 + (t >> 4);
        int n = nb + nl;
        int f = (t & 15) * 8;
        if (n < NN) {
            int s0 = offsets[n];
            int d = offsets[n + 1] - s0;
            f32x4 sum0 = {0.f,0.f,0.f,0.f}, sum1 = {0.f,0.f,0.f,0.f};
            f32x4 mx0 = {-INFINITY,-INFINITY,-INFINITY,-INFINITY};
            f32x4 mx1 = mx0;
            int i = 0;
            for (; i + 2 <= d; i += 2) {
                int p0 = perm[s0 + i], p1 = perm[s0 + i + 1];
                const short* h0 = hw0 + (size_t)(p0 & 16383) * HD + f;
                const short* h1 = hw0 + (size_t)(p1 & 16383) * HD + f;
                const float* t0 = btab + (p0 >> 14) * HD + f;
                const float* t1 = btab + (p1 >> 14) * HD + f;
                bf16x4 a00 = *(const bf16x4*)h0, a01 = *(const bf16x4*)(h0 + 4);
                bf16x4 a10 = *(const bf16x4*)h1, a11 = *(const bf16x4*)(h1 + 4);
                f32x4 b00 = *(const f32x4*)t0, b01 = *(const f32x4*)(t0 + 4);
                f32x4 b10 = *(const f32x4*)t1, b11 = *(const f32x4*)(t1 + 4);
                f32x4 v00, v01, v10, v11;
                #pragma unroll
                for (int q = 0; q < 4; ++q) {
                    v00[q] = bf2f(a00[q]) + b00[q];
                    v01[q] = bf2f(a01[q]) + b01[q];
                    v10[q] = bf2f(a10[q]) + b10[q];
                    v11[q] = bf2f(a11[q]) + b11[q];
                }
                sum0 += v00 + v10; sum1 += v01 + v11;
                #pragma unroll
                for (int q = 0; q < 4; ++q) {
                    mx0[q] = fmaxf(mx0[q], fmaxf(v00[q], v10[q]));
                    mx1[q] = fmaxf(mx1[q], fmaxf(v01[q], v11[q]));
                }
            }
            if (i < d) {
                int p0 = perm[s0 + i];
                const short* h0 = hw0 + (size_t)(p0 & 16383) * HD + f;
                const float* t0 = btab + (p0 >> 14) * HD + f;
                bf16x4 a00 = *(const bf16x4*)h0, a01 = *(const bf16x4*)(h0 + 4);
                f32x4 b00 = *(const f32x4*)t0, b01 = *(const f32x4*)(t0 + 4);
                f32x4 v00, v01;
                #pragma unroll
                for (int q = 0; q < 4; ++q) {
                    v00[q] = bf2f(a00[q]) + b00[q];
                    v01[q] = bf2f(a01[q]) + b01[q];
                }
                sum0 += v00; sum1 += v01;
                #pragma unroll
                for (int q = 0; q < 4; ++q) {
                    mx0[q] = fmaxf(mx0[q], v00[q]);
                    mx1[q] = fmaxf(mx1[q], v01[q]);
                }
            }
            const float* cp = hw1 + (size_t)n * HD + f;
            f32x4 c0 = *(const f32x4*)cp, c1 = *(const f32x4*)(cp + 4);
            f32x4 me0, me1, so0, so1, mo0, mo1;
            if (d > 0) {
                float df = (float)d, di = 1.f / df;
                so0 = sum0 + df * c0;  so1 = sum1 + df * c1;
                me0 = sum0 * di + c0;  me1 = sum1 * di + c1;
                mo0 = mx0 + c0;        mo1 = mx1 + c1;
            } else {
                me0 = (f32x4){0.f,0.f,0.f,0.f}; me1 = me0;
                so0 = me0; so1 = me0; mo0 = me0; mo1 = me0;
            }
            *(f32x4*)&agg_s[nl][f]           = me0; *(f32x4*)&agg_s[nl][f + 4]       = me1;
            *(f32x4*)&agg_s[nl][128 + f]     = so0; *(f32x4*)&agg_s[nl][128 + f + 4] = so1;
            *(f32x4*)&agg_s[nl][256 + f]     = mo0; *(f32x4*)&agg_s[nl][256 + f + 4] = mo1;
        }
    }
    __syncthreads();

    // ---- Phase B: GEMM ----
    int wave = t >> 6, lane = t & 63;
    int mhalf = wave & 1, jhalf = wave >> 1;
    int lx = lane & 15, kb = lane >> 4;
    int frow = mhalf * 16 + lx;
    int arow = t >> 3, seg = t & 7;
    int an = nb + arow;
    bool aval = an < NN;
    float f_amp = 0.f, f_att = 0.f;
    if (aval) { f_amp = amp[an]; f_att = att[an]; }
    f32x4 acc[4];
    #pragma unroll
    for (int j = 0; j < 4; ++j) acc[j] = (f32x4){0.f, 0.f, 0.f, 0.f};

    for (int ks = 0; ks < 40; ++ks) {
        __syncthreads();
        {   // A: 32 rows x 32 k of hcat from LDS agg_s / global hin
            int r = ks >> 2;
            int kbase = (ks & 3) * 32 + seg * 4;
            float4 x = make_float4(0.f, 0.f, 0.f, 0.f);
            float fac = 1.f;
            if (aval) {
                if (r < 9) {
                    int ag = r % 3, fi = r / 3;
                    fac = (fi == 0) ? 1.f : ((fi == 1) ? f_amp : f_att);
                    x = *(const float4*)&agg_s[arow][ag * 128 + kbase];
                } else {
                    x = *(const float4*)(hin + (size_t)an * HD + kbase);
                }
            }
            bf16x4 pk;
            pk[0] = f2bf(x.x * fac); pk[1] = f2bf(x.y * fac);
            pk[2] = f2bf(x.z * fac); pk[3] = f2bf(x.w * fac);
            *(bf16x4*)&As[arow * 40 + seg * 4] = pk;
        }
        {   // B: 128 rows x 32 shorts, blocked contiguous
            int brow = t >> 1, bh = t & 1;
            const short* src = Wt + (size_t)ks * 4096 + (size_t)brow * 32 + bh * 16;
            *(bf16x8*)&Bs[brow * 40 + bh * 16] = *(const bf16x8*)src;
            *(bf16x8*)&Bs[brow * 40 + bh * 16 + 8] = *(const bf16x8*)(src + 8);
        }
        __syncthreads();
        bf16x8 a = *(const bf16x8*)&As[frow * 40 + kb * 8];
        #pragma unroll
        for (int jj = 0; jj < 4; ++jj) {
            int j = jhalf * 64 + jj * 16 + lx;
            bf16x8 bfr = *(const bf16x8*)&Bs[j * 40 + kb * 8];
            acc[jj] = __builtin_amdgcn_mfma_f32_16x16x32_bf16(a, bfr, acc[jj], 0, 0, 0);
        }
    }
    #pragma unroll
    for (int jj = 0; jj < 4; ++jj) {
        int c = jhalf * 64 + jj * 16 + lx;
        float bc = bias[c];
        #pragma unroll
        for (int r_ = 0; r_ < 4; ++r_) {
            int n2 = nb + mhalf * 16 + kb * 4 + r_;
            if (n2 < NN) {
                size_t off = (size_t)n2 * HD + c;
                hout[off] = acc[jj][r_] + bc + hin[off];
            }
        }
    }
}

// Fused deterministic graph pooling + output MLP. One block per graph (batch sorted).
__global__ __launch_bounds__(256) void pool_out_kernel(
    const float* __restrict__ h, const int* __restrict__ batch,
    const float* __restrict__ W1, const float* __restrict__ b1,
    const float* __restrict__ W2, const float* __restrict__ b2,
    float* __restrict__ out)
{
    __shared__ float rs[384];
    __shared__ float red[256];
    __shared__ float s2[128], m2[128];
    int g = blockIdx.x, t = threadIdx.x;
    int lo = 0, hi = NN;
    while (lo < hi) { int mid = (lo + hi) >> 1; if (batch[mid] < g) lo = mid + 1; else hi = mid; }
    int lo2 = lo, hi2 = NN;
    while (lo2 < hi2) { int mid = (lo2 + hi2) >> 1; if (batch[mid] < g + 1) lo2 = mid + 1; else hi2 = mid; }
    int cnt = lo2 - lo;
    int f = t & 127, grp = t >> 7;
    float sum = 0.f, mx = -INFINITY;
    for (int n = lo + grp; n < lo2; n += 2) {
        float v = h[(size_t)n * HD + f];
        sum += v; mx = fmaxf(mx, v);
    }
    if (grp == 1) { s2[f] = sum; m2[f] = mx; }
    __syncthreads();
    if (grp == 0) {
        sum += s2[f]; mx = fmaxf(mx, m2[f]);
        float mean = (cnt > 0) ? sum / (float)cnt : 0.f;
        float so = (cnt > 0) ? sum : 0.f;
        float mo = (cnt > 0) ? mx : 0.f;
        if (isnan(mean) || isinf(mean)) mean = 0.f;
        if (isnan(so) || isinf(so)) so = 0.f;
        if (isnan(mo) || isinf(mo)) mo = 0.f;
        rs[f] = mean; rs[128 + f] = so; rs[256 + f] = mo;
    }
    __syncthreads();
    {
        int j = t & 127, kh = t >> 7;
        float acc = 0.f;
        for (int k = kh * 192; k < kh * 192 + 192; ++k)
            acc = fmaf(rs[k], W1[k * HD + j], acc);
        red[t] = acc;
    }
    __syncthreads();
    if (t < 128) {
        float v = fmaxf(red[t] + red[128 + t] + b1[t], 0.f);
        red[t] = v * W2[t];
    }
    __syncthreads();
    for (int s = 64; s > 0; s >>= 1) {
        if (t < s) red[t] += red[t + s];
        __syncthreads();
    }
    if (t == 0) {
        float o = red[0] + b2[0];
        if (isnan(o) || isinf(o)) o = 0.f;
        out[g] = o;
    }
}

extern "C" void kernel_launch(void* const* d_in, const int* in_sizes, int n_in,
                              void* d_out, int out_size, void* d_ws, size_t ws_size,
                              hipStream_t stream)
{
    const int* x          = (const int*)d_in[0];
    const int* ei         = (const int*)d_in[1];
    const int* ea         = (const int*)d_in[2];
    const int* batch      = (const int*)d_in[3];
    const float* atom_emb = (const float*)d_in[4];
    const float* bond_emb = (const float*)d_in[5];
    const float* pre_W    = (const float*)d_in[6];
    const float* pre_b    = (const float*)d_in[7];
    const float* post_W   = (const float*)d_in[8];
    const float* post_b   = (const float*)d_in[9];
    const float* out_W1   = (const float*)d_in[10];
    const float* out_b1   = (const float*)d_in[11];
    const float* out_W2   = (const float*)d_in[12];
    const float* out_b2   = (const float*)d_in[13];
    float* out = (float*)d_out;
    const int* row = ei;
    const int* col = ei + NE;

    char* p = (char*)d_ws;
    auto alloc = [&](size_t bytes) { char* r = p; p += (bytes + 255) & ~(size_t)255; return r; };
    float*    deg     = (float*)alloc((size_t)NN * 4);
    float*    amp     = (float*)alloc((size_t)NN * 4);
    float*    att     = (float*)alloc((size_t)NN * 4);
    int*      offsets = (int*)alloc((size_t)(NN + 1) * 4);
    int*      cursor  = (int*)alloc((size_t)NN * 4);
    int*      perm    = (int*)alloc((size_t)NE * 4);
    float*    hA      = (float*)alloc((size_t)NN * HD * 4);
    float*    hB      = (float*)alloc((size_t)NN * HD * 4);
    short*    hw0     = (short*)alloc((size_t)NN * HD * 2);
    float*    hw1     = (float*)alloc((size_t)NN * HD * 4);
    float*    btab    = (float*)alloc((size_t)NL * 5 * HD * 4);
    short*    pre_Wt  = (short*)alloc((size_t)NL * 4 * 256 * 32 * 2);
    short*    post_Wt = (short*)alloc((size_t)NL * 40 * 128 * 32 * 2);

    embed_kernel<<<(NN * HD) / 256, 256, 0, stream>>>(x, atom_emb, hA, deg, cursor);
    deg_kernel<<<(NE + 255) / 256, 256, 0, stream>>>(col, deg);
    scan_facs_kernel<<<1, 1024, 0, stream>>>(deg, offsets, amp, att);
    scatter_kernel<<<(NE + 255) / 256, 256, 0, stream>>>(row, col, ea, offsets, cursor, perm);
    convw_bondtab_kernel<<<20 + (NL * 40 * 128 * 32 + 255) / 256, 256, 0, stream>>>(
        bond_emb, pre_W, pre_b, post_W, btab, pre_Wt, post_Wt);

    float* curH = hA;
    float* nxtH = hB;
    for (int l = 0; l < NL; ++l) {
        pre_gemm_mfma<<<dim3((NN + 31) / 32, 2), 128, 0, stream>>>(
            curH, pre_Wt + (size_t)l * 4 * 256 * 32, hw0, hw1);
        agg_node_gemm_mfma<<<(NN + 31) / 32, 256, 0, stream>>>(
            hw0, hw1, btab + (size_t)l * 5 * HD, offsets, perm,
            curH, amp, att, post_Wt + (size_t)l * 40 * 128 * 32,
            post_b + (size_t)l * HD, nxtH);
        float* tmp = curH; curH = nxtH; nxtH = tmp;
    }

    pool_out_kernel<<<NG, 256, 0, stream>>>(curH, batch, out_W1, out_b1, out_W2, out_b2, out);
}

// Round 9
// 299.627 us; speedup vs baseline: 1.3697x; 1.3267x over previous
//
#include <hip/hip_runtime.h>
#include <hip/hip_bf16.h>
#include <math.h>

#define NN 10000
#define NE 160000
#define HD 128
#define NL 4
#define NG 64

typedef __attribute__((ext_vector_type(8))) short bf16x8;
typedef __attribute__((ext_vector_type(4))) short bf16x4;
typedef __attribute__((ext_vector_type(4))) float f32x4;

// fp32 -> bf16 (round to nearest even), finite inputs
static __device__ __forceinline__ short f2bf(float f) {
    unsigned u = __float_as_uint(f);
    unsigned r = (u + 0x7FFFu + ((u >> 16) & 1u)) >> 16;
    return (short)r;
}
static __device__ __forceinline__ float bf2f(short s) {
    return __uint_as_float(((unsigned)(unsigned short)s) << 16);
}

__global__ void embed_kernel(const int* __restrict__ x, const float* __restrict__ atom_emb,
                             float* __restrict__ h, float* __restrict__ deg,
                             int* __restrict__ cursor) {
    int idx = blockIdx.x * 256 + threadIdx.x;
    if (idx < NN) { deg[idx] = 0.f; cursor[idx] = 0; }
    if (idx < NN * HD) {
        int n = idx >> 7, f = idx & 127;
        h[idx] = atom_emb[x[n] * HD + f];
    }
}

__global__ void deg_kernel(const int* __restrict__ col, float* __restrict__ deg) {
    int e = blockIdx.x * 256 + threadIdx.x;
    if (e < NE) atomicAdd(&deg[col[e]], 1.f);
}

// One-pass parallel exclusive scan (1024 thr x 10 elems) + amp/att factors.
__global__ __launch_bounds__(1024) void scan_facs_kernel(const float* __restrict__ deg,
                                                         int* __restrict__ offsets,
                                                         float* __restrict__ amp,
                                                         float* __restrict__ att) {
    __shared__ int s[1024];
    int t = threadIdx.x;
    int base = t * 10;
    int v[10];
    int lsum = 0;
    #pragma unroll
    for (int i = 0; i < 10; ++i) {
        int idx = base + i;
        int d = (idx < NN) ? (int)deg[idx] : 0;
        v[i] = d;
        lsum += d;
        if (idx < NN) {
            float logD = logf((float)d + 1.f);
            amp[idx] = logD;                       // / AVG_D_LOG (=1.0)
            att[idx] = 1.f / fmaxf(logD, 1e-8f);   // AVG_D_LOG / max(logD, eps)
        }
    }
    s[t] = lsum;
    __syncthreads();
    for (int off = 1; off < 1024; off <<= 1) {
        int x2 = (t >= off) ? s[t - off] : 0;
        __syncthreads();
        s[t] += x2;
        __syncthreads();
    }
    int run = s[t] - lsum;
    #pragma unroll
    for (int i = 0; i < 10; ++i) {
        int idx = base + i;
        if (idx < NN) offsets[idx] = run;
        run += v[i];
    }
    if (t == 1023) offsets[NN] = run;   // = NE
}

__global__ void scatter_kernel(const int* __restrict__ row, const int* __restrict__ col,
                               const int* __restrict__ ea, const int* __restrict__ offsets,
                               int* __restrict__ cursor, int* __restrict__ perm) {
    int e = blockIdx.x * 256 + threadIdx.x;
    if (e < NE) {
        int c = col[e];
        int pos = offsets[c] + atomicAdd(&cursor[c], 1);
        perm[pos] = row[e] | (ea[e] << 14);   // row < 16384, ea < 5
    }
}

// Fused: blocks 0..19 compute btab; remaining blocks convert weights to bf16 K-blocked:
//   pre_Wt[l][kblk<4][j<256][k<32], post_Wt[l][kblk<40][j<128][k<32]
__global__ __launch_bounds__(256) void convw_bondtab_kernel(
    const float* __restrict__ bond_emb,
    const float* __restrict__ pre_W, const float* __restrict__ pre_b,
    const float* __restrict__ post_W,
    float* __restrict__ btab, short* __restrict__ pre_Wt, short* __restrict__ post_Wt) {
    int b = blockIdx.x;
    if (b < 20) {
        if (threadIdx.x < 128) {
            int l = b / 5, bb = b % 5;
            int f = threadIdx.x;
            const float* W2 = pre_W + (size_t)l * 384 * HD + 256 * HD;
            const float* eb = bond_emb + bb * HD;
            float acc = pre_b[l * HD + f];
            for (int k = 0; k < HD; ++k) acc = fmaf(eb[k], W2[k * HD + f], acc);
            btab[(l * 5 + bb) * HD + f] = acc;
        }
        return;
    }
    int idx = (b - 20) * 256 + threadIdx.x;
    if (idx < NL * 4 * 256 * 32) {      // 131072
        int l = idx >> 15;
        int r = idx & 32767;
        int kblk = r >> 13;
        int rr = r & 8191;
        int j = rr >> 5, k = rr & 31;
        const float* Wl = pre_W + (size_t)l * 384 * HD;
        float v = (j < 128) ? Wl[(kblk * 32 + k) * HD + j]
                            : Wl[(128 + kblk * 32 + k) * HD + (j - 128)];
        pre_Wt[idx] = f2bf(v);
    }
    if (idx < NL * 40 * 128 * 32) {     // 655360
        int l = idx / 163840;
        int r = idx % 163840;
        int kblk = r >> 12;
        int rr = r & 4095;
        int j = rr >> 5, k = rr & 31;
        post_Wt[idx] = f2bf(post_W[(size_t)l * 163840 + (size_t)(kblk * 32 + k) * HD + j]);
    }
}

// hw0[n] = h[n] @ W0 (bf16), hw1[n] = h[n] @ W1 (fp32).
// 16 nodes/block, 256 thr = 4 waves x 64 cols each. Barrier-free K-loop, global B.
__global__ __launch_bounds__(256) void pre_gemm_mfma(const float* __restrict__ h,
                                                     const short* __restrict__ Wt, // [4][256][32]
                                                     short* __restrict__ hw0,
                                                     float* __restrict__ hw1) {
    __shared__ short Ap[16][136];
    int t = threadIdx.x;
    int nb = blockIdx.x * 16;
    {   // stage A-panel: 16 nodes x 128 k, fp32 -> bf16
        int nl = t >> 4, f = (t & 15) * 8;
        int n = nb + nl;
        const float* src = h + (size_t)n * HD + f;
        float4 x0 = *(const float4*)src, x1 = *(const float4*)(src + 4);
        bf16x8 pk;
        pk[0]=f2bf(x0.x); pk[1]=f2bf(x0.y); pk[2]=f2bf(x0.z); pk[3]=f2bf(x0.w);
        pk[4]=f2bf(x1.x); pk[5]=f2bf(x1.y); pk[6]=f2bf(x1.z); pk[7]=f2bf(x1.w);
        *(bf16x8*)&Ap[nl][f] = pk;
    }
    __syncthreads();
    int wave = t >> 6, lane = t & 63;
    int lx = lane & 15, kb = lane >> 4;
    f32x4 acc[4];
    #pragma unroll
    for (int j = 0; j < 4; ++j) acc[j] = (f32x4){0.f, 0.f, 0.f, 0.f};

    for (int ks = 0; ks < 4; ++ks) {
        bf16x8 a = *(const bf16x8*)&Ap[lx][ks * 32 + kb * 8];
        const short* bp = Wt + (size_t)ks * 8192 + (size_t)(wave * 64 + lx) * 32 + kb * 8;
        #pragma unroll
        for (int jj = 0; jj < 4; ++jj) {
            bf16x8 bfr = *(const bf16x8*)(bp + jj * 512);
            acc[jj] = __builtin_amdgcn_mfma_f32_16x16x32_bf16(a, bfr, acc[jj], 0, 0, 0);
        }
    }
    #pragma unroll
    for (int jj = 0; jj < 4; ++jj) {
        int c = wave * 64 + jj * 16 + lx;
        #pragma unroll
        for (int r_ = 0; r_ < 4; ++r_) {
            int n2 = nb + kb * 4 + r_;
            if (c < 128) hw0[(size_t)n2 * HD + c] = f2bf(acc[jj][r_]);
            else         hw1[(size_t)n2 * HD + (c - 128)] = acc[jj][r_];
        }
    }
}

// FUSED: Phase A = CSR aggregation of 16 nodes -> full bf16 A-panel (pre-scaled hcat) in LDS;
// Phase B = barrier-free MFMA GEMM (A from LDS, B direct from global L2); bias+residual fused.
// A-panel k-layout: r<9 at [r*128,+128): agg[r%3] * {1,amp,att}[r/3]; r==9: h_in.
__global__ __launch_bounds__(256) void agg_node_gemm_mfma(
    const short* __restrict__ hw0, const float* __restrict__ hw1,
    const float* __restrict__ btab,
    const int* __restrict__ offsets, const int* __restrict__ perm,
    const float* __restrict__ hin,
    const float* __restrict__ amp, const float* __restrict__ att,
    const short* __restrict__ Wt /* [40][128][32] */, const float* __restrict__ bias,
    float* __restrict__ hout) {
    __shared__ short Ap[16][1288];     // 16 nodes x K=1280 bf16 (+8 pad)
    __shared__ float btab_s[5][128];
    int t = threadIdx.x;
    int nb = blockIdx.x * 16;

    if (t < 160) {   // stage bond table (5 x 128 fp32)
        int b = t >> 5, f4 = (t & 31) * 4;
        *(f32x4*)&btab_s[b][f4] = *(const f32x4*)(btab + b * HD + f4);
    }
    __syncthreads();

    // ---- Phase A: one thread owns (node, 8 feats) ----
    {
        int nl = t >> 4;
        int n = nb + nl;
        int f = (t & 15) * 8;
        int s0 = offsets[n];
        int d = offsets[n + 1] - s0;
        f32x4 sum0 = {0.f,0.f,0.f,0.f}, sum1 = {0.f,0.f,0.f,0.f};
        f32x4 mx0 = {-INFINITY,-INFINITY,-INFINITY,-INFINITY};
        f32x4 mx1 = mx0;
        int i = 0;
        for (; i + 2 <= d; i += 2) {
            int p0 = perm[s0 + i], p1 = perm[s0 + i + 1];
            bf16x8 a0 = *(const bf16x8*)(hw0 + (size_t)(p0 & 16383) * HD + f);
            bf16x8 a1 = *(const bf16x8*)(hw0 + (size_t)(p1 & 16383) * HD + f);
            const float* t0 = &btab_s[p0 >> 14][f];
            const float* t1 = &btab_s[p1 >> 14][f];
            f32x4 b00 = *(const f32x4*)t0, b01 = *(const f32x4*)(t0 + 4);
            f32x4 b10 = *(const f32x4*)t1, b11 = *(const f32x4*)(t1 + 4);
            f32x4 v00, v01, v10, v11;
            #pragma unroll
            for (int q = 0; q < 4; ++q) {
                v00[q] = bf2f(a0[q]) + b00[q];
                v01[q] = bf2f(a0[q + 4]) + b01[q];
                v10[q] = bf2f(a1[q]) + b10[q];
                v11[q] = bf2f(a1[q + 4]) + b11[q];
            }
            sum0 += v00 + v10; sum1 += v01 + v11;
            #pragma unroll
            for (int q = 0; q < 4; ++q) {
                mx0[q] = fmaxf(mx0[q], fmaxf(v00[q], v10[q]));
                mx1[q] = fmaxf(mx1[q], fmaxf(v01[q], v11[q]));
            }
        }
        if (i < d) {
            int p0 = perm[s0 + i];
            bf16x8 a0 = *(const bf16x8*)(hw0 + (size_t)(p0 & 16383) * HD + f);
            const float* t0 = &btab_s[p0 >> 14][f];
            f32x4 b00 = *(const f32x4*)t0, b01 = *(const f32x4*)(t0 + 4);
            f32x4 v00, v01;
            #pragma unroll
            for (int q = 0; q < 4; ++q) {
                v00[q] = bf2f(a0[q]) + b00[q];
                v01[q] = bf2f(a0[q + 4]) + b01[q];
            }
            sum0 += v00; sum1 += v01;
            #pragma unroll
            for (int q = 0; q < 4; ++q) {
                mx0[q] = fmaxf(mx0[q], v00[q]);
                mx1[q] = fmaxf(mx1[q], v01[q]);
            }
        }
        const float* cp = hw1 + (size_t)n * HD + f;
        f32x4 c0 = *(const f32x4*)cp, c1 = *(const f32x4*)(cp + 4);
        f32x4 me0, me1, so0, so1, mo0, mo1;
        if (d > 0) {
            float df = (float)d, di = 1.f / df;
            so0 = sum0 + df * c0;  so1 = sum1 + df * c1;
            me0 = sum0 * di + c0;  me1 = sum1 * di + c1;
            mo0 = mx0 + c0;        mo1 = mx1 + c1;
        } else {
            me0 = (f32x4){0.f,0.f,0.f,0.f}; me1 = me0;
            so0 = me0; so1 = me0; mo0 = me0; mo1 = me0;
        }
        float f_amp = amp[n], f_att = att[n];
        #pragma unroll
        for (int fi = 0; fi < 3; ++fi) {
            float fac = (fi == 0) ? 1.f : ((fi == 1) ? f_amp : f_att);
            #pragma unroll
            for (int ag = 0; ag < 3; ++ag) {
                f32x4 r0 = (ag == 0) ? me0 : ((ag == 1) ? so0 : mo0);
                f32x4 r1 = (ag == 0) ? me1 : ((ag == 1) ? so1 : mo1);
                bf16x8 pk;
                #pragma unroll
                for (int q = 0; q < 4; ++q) {
                    pk[q]     = f2bf(r0[q] * fac);
                    pk[q + 4] = f2bf(r1[q] * fac);
                }
                *(bf16x8*)&Ap[nl][(fi * 3 + ag) * 128 + f] = pk;
            }
        }
        {   // region 9: h_in
            const float* src = hin + (size_t)n * HD + f;
            float4 x0 = *(const float4*)src, x1 = *(const float4*)(src + 4);
            bf16x8 pk;
            pk[0]=f2bf(x0.x); pk[1]=f2bf(x0.y); pk[2]=f2bf(x0.z); pk[3]=f2bf(x0.w);
            pk[4]=f2bf(x1.x); pk[5]=f2bf(x1.y); pk[6]=f2bf(x1.z); pk[7]=f2bf(x1.w);
            *(bf16x8*)&Ap[nl][9 * 128 + f] = pk;
        }
    }
    __syncthreads();

    // ---- Phase B: barrier-free GEMM; wave w owns cols [w*32, w*32+32) ----
    int wave = t >> 6, lane = t & 63;
    int lx = lane & 15, kb = lane >> 4;
    f32x4 acc0 = {0.f,0.f,0.f,0.f}, acc1 = acc0;
    for (int ks = 0; ks < 40; ++ks) {
        bf16x8 a = *(const bf16x8*)&Ap[lx][ks * 32 + kb * 8];
        const short* bp = Wt + (size_t)ks * 4096 + (size_t)(wave * 32 + lx) * 32 + kb * 8;
        bf16x8 b0 = *(const bf16x8*)bp;
        bf16x8 b1 = *(const bf16x8*)(bp + 512);
        acc0 = __builtin_amdgcn_mfma_f32_16x16x32_bf16(a, b0, acc0, 0, 0, 0);
        acc1 = __builtin_amdgcn_mfma_f32_16x16x32_bf16(a, b1, acc1, 0, 0, 0);
    }
    #pragma unroll
    for (int jj = 0; jj < 2; ++jj) {
        int c = wave * 32 + jj * 16 + lx;
        float bc = bias[c];
        f32x4 av = jj ? acc1 : acc0;
        #pragma unroll
        for (int r_ = 0; r_ < 4; ++r_) {
            int n2 = nb + kb * 4 + r_;
            size_t off = (size_t)n2 * HD + c;
            hout[off] = av[r_] + bc + hin[off];
        }
    }
}

// Fused deterministic graph pooling + output MLP. One block per graph (batch sorted).
__global__ __launch_bounds__(256) void pool_out_kernel(
    const float* __restrict__ h, const int* __restrict__ batch,
    const float* __restrict__ W1, const float* __restrict__ b1,
    const float* __restrict__ W2, const float* __restrict__ b2,
    float* __restrict__ out)
{
    __shared__ float rs[384];
    __shared__ float red[256];
    __shared__ float s2[128], m2[128];
    int g = blockIdx.x, t = threadIdx.x;
    int lo = 0, hi = NN;
    while (lo < hi) { int mid = (lo + hi) >> 1; if (batch[mid] < g) lo = mid + 1; else hi = mid; }
    int lo2 = lo, hi2 = NN;
    while (lo2 < hi2) { int mid = (lo2 + hi2) >> 1; if (batch[mid] < g + 1) lo2 = mid + 1; else hi2 = mid; }
    int cnt = lo2 - lo;
    int f = t & 127, grp = t >> 7;
    float sum = 0.f, mx = -INFINITY;
    for (int n = lo + grp; n < lo2; n += 2) {
        float v = h[(size_t)n * HD + f];
        sum += v; mx = fmaxf(mx, v);
    }
    if (grp == 1) { s2[f] = sum; m2[f] = mx; }
    __syncthreads();
    if (grp == 0) {
        sum += s2[f]; mx = fmaxf(mx, m2[f]);
        float mean = (cnt > 0) ? sum / (float)cnt : 0.f;
        float so = (cnt > 0) ? sum : 0.f;
        float mo = (cnt > 0) ? mx : 0.f;
        if (isnan(mean) || isinf(mean)) mean = 0.f;
        if (isnan(so) || isinf(so)) so = 0.f;
        if (isnan(mo) || isinf(mo)) mo = 0.f;
        rs[f] = mean; rs[128 + f] = so; rs[256 + f] = mo;
    }
    __syncthreads();
    {
        int j = t & 127, kh = t >> 7;
        float acc = 0.f;
        for (int k = kh * 192; k < kh * 192 + 192; ++k)
            acc = fmaf(rs[k], W1[k * HD + j], acc);
        red[t] = acc;
    }
    __syncthreads();
    if (t < 128) {
        float v = fmaxf(red[t] + red[128 + t] + b1[t], 0.f);
        red[t] = v * W2[t];
    }
    __syncthreads();
    for (int s = 64; s > 0; s >>= 1) {
        if (t < s) red[t] += red[t + s];
        __syncthreads();
    }
    if (t == 0) {
        float o = red[0] + b2[0];
        if (isnan(o) || isinf(o)) o = 0.f;
        out[g] = o;
    }
}

extern "C" void kernel_launch(void* const* d_in, const int* in_sizes, int n_in,
                              void* d_out, int out_size, void* d_ws, size_t ws_size,
                              hipStream_t stream)
{
    const int* x          = (const int*)d_in[0];
    const int* ei         = (const int*)d_in[1];
    const int* ea         = (const int*)d_in[2];
    const int* batch      = (const int*)d_in[3];
    const float* atom_emb = (const float*)d_in[4];
    const float* bond_emb = (const float*)d_in[5];
    const float* pre_W    = (const float*)d_in[6];
    const float* pre_b    = (const float*)d_in[7];
    const float* post_W   = (const float*)d_in[8];
    const float* post_b   = (const float*)d_in[9];
    const float* out_W1   = (const float*)d_in[10];
    const float* out_b1   = (const float*)d_in[11];
    const float* out_W2   = (const float*)d_in[12];
    const float* out_b2   = (const float*)d_in[13];
    float* out = (float*)d_out;
    const int* row = ei;
    const int* col = ei + NE;

    char* p = (char*)d_ws;
    auto alloc = [&](size_t bytes) { char* r = p; p += (bytes + 255) & ~(size_t)255; return r; };
    float*    deg     = (float*)alloc((size_t)NN * 4);
    float*    amp     = (float*)alloc((size_t)NN * 4);
    float*    att     = (float*)alloc((size_t)NN * 4);
    int*      offsets = (int*)alloc((size_t)(NN + 1) * 4);
    int*      cursor  = (int*)alloc((size_t)NN * 4);
    int*      perm    = (int*)alloc((size_t)NE * 4);
    float*    hA      = (float*)alloc((size_t)NN * HD * 4);
    float*    hB      = (float*)alloc((size_t)NN * HD * 4);
    short*    hw0     = (short*)alloc((size_t)NN * HD * 2);
    float*    hw1     = (float*)alloc((size_t)NN * HD * 4);
    float*    btab    = (float*)alloc((size_t)NL * 5 * HD * 4);
    short*    pre_Wt  = (short*)alloc((size_t)NL * 4 * 256 * 32 * 2);
    short*    post_Wt = (short*)alloc((size_t)NL * 40 * 128 * 32 * 2);

    embed_kernel<<<(NN * HD) / 256, 256, 0, stream>>>(x, atom_emb, hA, deg, cursor);
    deg_kernel<<<(NE + 255) / 256, 256, 0, stream>>>(col, deg);
    scan_facs_kernel<<<1, 1024, 0, stream>>>(deg, offsets, amp, att);
    scatter_kernel<<<(NE + 255) / 256, 256, 0, stream>>>(row, col, ea, offsets, cursor, perm);
    convw_bondtab_kernel<<<20 + (NL * 40 * 128 * 32 + 255) / 256, 256, 0, stream>>>(
        bond_emb, pre_W, pre_b, post_W, btab, pre_Wt, post_Wt);

    float* curH = hA;
    float* nxtH = hB;
    for (int l = 0; l < NL; ++l) {
        pre_gemm_mfma<<<NN / 16, 256, 0, stream>>>(
            curH, pre_Wt + (size_t)l * 4 * 256 * 32, hw0, hw1);
        agg_node_gemm_mfma<<<NN / 16, 256, 0, stream>>>(
            hw0, hw1, btab + (size_t)l * 5 * HD, offsets, perm,
            curH, amp, att, post_Wt + (size_t)l * 40 * 128 * 32,
            post_b + (size_t)l * HD, nxtH);
        float* tmp = curH; curH = nxtH; nxtH = tmp;
    }

    pool_out_kernel<<<NG, 256, 0, stream>>>(curH, batch, out_W1, out_b1, out_W2, out_b2, out);
}

// Round 11
// 287.495 us; speedup vs baseline: 1.4275x; 1.0422x over previous
//
#include <hip/hip_runtime.h>
#include <hip/hip_bf16.h>
#include <math.h>

#define NN 10000
#define NE 160000
#define HD 128
#define NL 4
#define NG 64

typedef __attribute__((ext_vector_type(8))) short bf16x8;
typedef __attribute__((ext_vector_type(4))) short bf16x4;
typedef __attribute__((ext_vector_type(4))) float f32x4;

// fp32 -> bf16 (round to nearest even), finite inputs
static __device__ __forceinline__ short f2bf(float f) {
    unsigned u = __float_as_uint(f);
    unsigned r = (u + 0x7FFFu + ((u >> 16) & 1u)) >> 16;
    return (short)r;
}
static __device__ __forceinline__ float bf2f(short s) {
    return __uint_as_float(((unsigned)(unsigned short)s) << 16);
}

// setup1: embed h + clear deg/cursor
__global__ void setup1_kernel(const int* __restrict__ x, const float* __restrict__ atom_emb,
                              float* __restrict__ h, float* __restrict__ deg,
                              int* __restrict__ cursor) {
    int idx = blockIdx.x * 256 + threadIdx.x;
    if (idx < NN) { deg[idx] = 0.f; cursor[idx] = 0; }
    if (idx < NN * HD) {
        int n = idx >> 7, f = idx & 127;
        h[idx] = atom_emb[x[n] * HD + f];
    }
}

// setup2: blocks [0,625): deg histogram; blocks [625,645): btab; rest: weight conversion.
//   pre_Wt[l][kblk<4][j<256][k<32], post_Wt[l][kblk<40][j<128][k<32]
__global__ __launch_bounds__(256) void setup2_kernel(
    const int* __restrict__ col, float* __restrict__ deg,
    const float* __restrict__ bond_emb,
    const float* __restrict__ pre_W, const float* __restrict__ pre_b,
    const float* __restrict__ post_W,
    float* __restrict__ btab, short* __restrict__ pre_Wt, short* __restrict__ post_Wt) {
    int b = blockIdx.x;
    if (b < 625) {
        int e = b * 256 + threadIdx.x;
        if (e < NE) atomicAdd(&deg[col[e]], 1.f);
        return;
    }
    if (b < 645) {
        int lb = b - 625;
        if (threadIdx.x < 128) {
            int l = lb / 5, bb = lb % 5;
            int f = threadIdx.x;
            const float* W2 = pre_W + (size_t)l * 384 * HD + 256 * HD;
            const float* eb = bond_emb + bb * HD;
            float acc = pre_b[l * HD + f];
            for (int k = 0; k < HD; ++k) acc = fmaf(eb[k], W2[k * HD + f], acc);
            btab[(l * 5 + bb) * HD + f] = acc;
        }
        return;
    }
    int idx = (b - 645) * 256 + threadIdx.x;
    if (idx < NL * 4 * 256 * 32) {      // 131072
        int l = idx >> 15;
        int r = idx & 32767;
        int kblk = r >> 13;
        int rr = r & 8191;
        int j = rr >> 5, k = rr & 31;
        const float* Wl = pre_W + (size_t)l * 384 * HD;
        float v = (j < 128) ? Wl[(kblk * 32 + k) * HD + j]
                            : Wl[(128 + kblk * 32 + k) * HD + (j - 128)];
        pre_Wt[idx] = f2bf(v);
    }
    if (idx < NL * 40 * 128 * 32) {     // 655360
        int l = idx / 163840;
        int r = idx % 163840;
        int kblk = r >> 12;
        int rr = r & 4095;
        int j = rr >> 5, k = rr & 31;
        post_Wt[idx] = f2bf(post_W[(size_t)l * 163840 + (size_t)(kblk * 32 + k) * HD + j]);
    }
}

// One-pass parallel exclusive scan (1024 thr x 10 elems) + amp/att factors.
__global__ __launch_bounds__(1024) void scan_facs_kernel(const float* __restrict__ deg,
                                                         int* __restrict__ offsets,
                                                         float* __restrict__ amp,
                                                         float* __restrict__ att) {
    __shared__ int s[1024];
    int t = threadIdx.x;
    int base = t * 10;
    int v[10];
    int lsum = 0;
    #pragma unroll
    for (int i = 0; i < 10; ++i) {
        int idx = base + i;
        int d = (idx < NN) ? (int)deg[idx] : 0;
        v[i] = d;
        lsum += d;
        if (idx < NN) {
            float logD = logf((float)d + 1.f);
            amp[idx] = logD;                       // / AVG_D_LOG (=1.0)
            att[idx] = 1.f / fmaxf(logD, 1e-8f);   // AVG_D_LOG / max(logD, eps)
        }
    }
    s[t] = lsum;
    __syncthreads();
    for (int off = 1; off < 1024; off <<= 1) {
        int x2 = (t >= off) ? s[t - off] : 0;
        __syncthreads();
        s[t] += x2;
        __syncthreads();
    }
    int run = s[t] - lsum;
    #pragma unroll
    for (int i = 0; i < 10; ++i) {
        int idx = base + i;
        if (idx < NN) offsets[idx] = run;
        run += v[i];
    }
    if (t == 1023) offsets[NN] = run;   // = NE
}

__global__ void scatter_kernel(const int* __restrict__ row, const int* __restrict__ col,
                               const int* __restrict__ ea, const int* __restrict__ offsets,
                               int* __restrict__ cursor, int* __restrict__ perm) {
    int e = blockIdx.x * 256 + threadIdx.x;
    if (e < NE) {
        int c = col[e];
        int pos = offsets[c] + atomicAdd(&cursor[c], 1);
        perm[pos] = row[e] | (ea[e] << 14);   // row < 16384, ea < 5
    }
}

// Standalone first-layer projection: hw0[n] = h[n] @ W0 (bf16), hw1[n] = h[n] @ W1 (fp32).
// 16 nodes/block, 4 waves x 64 cols. Barrier-free K-loop, global B.
__global__ __launch_bounds__(256) void pre_gemm_mfma(const float* __restrict__ h,
                                                     const short* __restrict__ Wt, // [4][256][32]
                                                     short* __restrict__ hw0,
                                                     float* __restrict__ hw1) {
    __shared__ short Ap[16][136];
    int t = threadIdx.x;
    int nb = blockIdx.x * 16;
    {   // stage A-panel: 16 nodes x 128 k, fp32 -> bf16
        int nl = t >> 4, f = (t & 15) * 8;
        int n = nb + nl;
        const float* src = h + (size_t)n * HD + f;
        float4 x0 = *(const float4*)src, x1 = *(const float4*)(src + 4);
        bf16x8 pk;
        pk[0]=f2bf(x0.x); pk[1]=f2bf(x0.y); pk[2]=f2bf(x0.z); pk[3]=f2bf(x0.w);
        pk[4]=f2bf(x1.x); pk[5]=f2bf(x1.y); pk[6]=f2bf(x1.z); pk[7]=f2bf(x1.w);
        *(bf16x8*)&Ap[nl][f] = pk;
    }
    __syncthreads();
    int wave = t >> 6, lane = t & 63;
    int lx = lane & 15, kb = lane >> 4;
    f32x4 acc[4];
    #pragma unroll
    for (int j = 0; j < 4; ++j) acc[j] = (f32x4){0.f, 0.f, 0.f, 0.f};

    for (int ks = 0; ks < 4; ++ks) {
        bf16x8 a = *(const bf16x8*)&Ap[lx][ks * 32 + kb * 8];
        const short* bp = Wt + (size_t)ks * 8192 + (size_t)(wave * 64 + lx) * 32 + kb * 8;
        #pragma unroll
        for (int jj = 0; jj < 4; ++jj) {
            bf16x8 bfr = *(const bf16x8*)(bp + jj * 512);
            acc[jj] = __builtin_amdgcn_mfma_f32_16x16x32_bf16(a, bfr, acc[jj], 0, 0, 0);
        }
    }
    #pragma unroll
    for (int jj = 0; jj < 4; ++jj) {
        int c = wave * 64 + jj * 16 + lx;
        #pragma unroll
        for (int r_ = 0; r_ < 4; ++r_) {
            int n2 = nb + kb * 4 + r_;
            if (c < 128) hw0[(size_t)n2 * HD + c] = f2bf(acc[jj][r_]);
            else         hw1[(size_t)n2 * HD + (c - 128)] = acc[jj][r_];
        }
    }
}

// FUSED: Phase A = CSR aggregation of 16 nodes -> bf16 A-panel (pre-scaled hcat) in LDS;
// Phase B = barrier-free MFMA GEMM (A LDS, B global); bias+residual fused ->
// Epilogue (if nextWt): project hout with next layer's pre-weights -> hw0n/hw1n.
__global__ __launch_bounds__(256) void agg_node_gemm_mfma(
    const short* __restrict__ hw0, const float* __restrict__ hw1,
    const float* __restrict__ btab,
    const int* __restrict__ offsets, const int* __restrict__ perm,
    const float* __restrict__ hin,
    const float* __restrict__ amp, const float* __restrict__ att,
    const short* __restrict__ Wt /* [40][128][32] */, const float* __restrict__ bias,
    float* __restrict__ hout,
    const short* __restrict__ nextWt /* [4][256][32] or null */,
    short* __restrict__ hw0n, float* __restrict__ hw1n) {
    __shared__ short Ap[16][1288];     // 16 nodes x K=1280 bf16 (+8 pad)
    __shared__ short Ap2[16][136];     // next-layer staging
    __shared__ float btab_s[5][128];
    int t = threadIdx.x;
    int nb = blockIdx.x * 16;

    if (t < 160) {   // stage bond table (5 x 128 fp32)
        int b = t >> 5, f4 = (t & 31) * 4;
        *(f32x4*)&btab_s[b][f4] = *(const f32x4*)(btab + b * HD + f4);
    }
    __syncthreads();

    // ---- Phase A: one thread owns (node, 8 feats) ----
    {
        int nl = t >> 4;
        int n = nb + nl;
        int f = (t & 15) * 8;
        int s0 = offsets[n];
        int d = offsets[n + 1] - s0;
        f32x4 sum0 = {0.f,0.f,0.f,0.f}, sum1 = {0.f,0.f,0.f,0.f};
        f32x4 mx0 = {-INFINITY,-INFINITY,-INFINITY,-INFINITY};
        f32x4 mx1 = mx0;
        int i = 0;
        for (; i + 2 <= d; i += 2) {
            int p0 = perm[s0 + i], p1 = perm[s0 + i + 1];
            bf16x8 a0 = *(const bf16x8*)(hw0 + (size_t)(p0 & 16383) * HD + f);
            bf16x8 a1 = *(const bf16x8*)(hw0 + (size_t)(p1 & 16383) * HD + f);
            const float* t0 = &btab_s[p0 >> 14][f];
            const float* t1 = &btab_s[p1 >> 14][f];
            f32x4 b00 = *(const f32x4*)t0, b01 = *(const f32x4*)(t0 + 4);
            f32x4 b10 = *(const f32x4*)t1, b11 = *(const f32x4*)(t1 + 4);
            f32x4 v00, v01, v10, v11;
            #pragma unroll
            for (int q = 0; q < 4; ++q) {
                v00[q] = bf2f(a0[q]) + b00[q];
                v01[q] = bf2f(a0[q + 4]) + b01[q];
                v10[q] = bf2f(a1[q]) + b10[q];
                v11[q] = bf2f(a1[q + 4]) + b11[q];
            }
            sum0 += v00 + v10; sum1 += v01 + v11;
            #pragma unroll
            for (int q = 0; q < 4; ++q) {
                mx0[q] = fmaxf(mx0[q], fmaxf(v00[q], v10[q]));
                mx1[q] = fmaxf(mx1[q], fmaxf(v01[q], v11[q]));
            }
        }
        if (i < d) {
            int p0 = perm[s0 + i];
            bf16x8 a0 = *(const bf16x8*)(hw0 + (size_t)(p0 & 16383) * HD + f);
            const float* t0 = &btab_s[p0 >> 14][f];
            f32x4 b00 = *(const f32x4*)t0, b01 = *(const f32x4*)(t0 + 4);
            f32x4 v00, v01;
            #pragma unroll
            for (int q = 0; q < 4; ++q) {
                v00[q] = bf2f(a0[q]) + b00[q];
                v01[q] = bf2f(a0[q + 4]) + b01[q];
            }
            sum0 += v00; sum1 += v01;
            #pragma unroll
            for (int q = 0; q < 4; ++q) {
                mx0[q] = fmaxf(mx0[q], v00[q]);
                mx1[q] = fmaxf(mx1[q], v01[q]);
            }
        }
        const float* cp = hw1 + (size_t)n * HD + f;
        f32x4 c0 = *(const f32x4*)cp, c1 = *(const f32x4*)(cp + 4);
        f32x4 me0, me1, so0, so1, mo0, mo1;
        if (d > 0) {
            float df = (float)d, di = 1.f / df;
            so0 = sum0 + df * c0;  so1 = sum1 + df * c1;
            me0 = sum0 * di + c0;  me1 = sum1 * di + c1;
            mo0 = mx0 + c0;        mo1 = mx1 + c1;
        } else {
            me0 = (f32x4){0.f,0.f,0.f,0.f}; me1 = me0;
            so0 = me0; so1 = me0; mo0 = me0; mo1 = me0;
        }
        float f_amp = amp[n], f_att = att[n];
        #pragma unroll
        for (int fi = 0; fi < 3; ++fi) {
            float fac = (fi == 0) ? 1.f : ((fi == 1) ? f_amp : f_att);
            #pragma unroll
            for (int ag = 0; ag < 3; ++ag) {
                f32x4 r0 = (ag == 0) ? me0 : ((ag == 1) ? so0 : mo0);
                f32x4 r1 = (ag == 0) ? me1 : ((ag == 1) ? so1 : mo1);
                bf16x8 pk;
                #pragma unroll
                for (int q = 0; q < 4; ++q) {
                    pk[q]     = f2bf(r0[q] * fac);
                    pk[q + 4] = f2bf(r1[q] * fac);
                }
                *(bf16x8*)&Ap[nl][(fi * 3 + ag) * 128 + f] = pk;
            }
        }
        {   // region 9: h_in
            const float* src = hin + (size_t)n * HD + f;
            float4 x0 = *(const float4*)src, x1 = *(const float4*)(src + 4);
            bf16x8 pk;
            pk[0]=f2bf(x0.x); pk[1]=f2bf(x0.y); pk[2]=f2bf(x0.z); pk[3]=f2bf(x0.w);
            pk[4]=f2bf(x1.x); pk[5]=f2bf(x1.y); pk[6]=f2bf(x1.z); pk[7]=f2bf(x1.w);
            *(bf16x8*)&Ap[nl][9 * 128 + f] = pk;
        }
    }
    __syncthreads();

    // ---- Phase B: barrier-free GEMM; wave w owns cols [w*32, w*32+32) ----
    int wave = t >> 6, lane = t & 63;
    int lx = lane & 15, kb = lane >> 4;
    f32x4 acc0 = {0.f,0.f,0.f,0.f}, acc1 = acc0;
    for (int ks = 0; ks < 40; ++ks) {
        bf16x8 a = *(const bf16x8*)&Ap[lx][ks * 32 + kb * 8];
        const short* bp = Wt + (size_t)ks * 4096 + (size_t)(wave * 32 + lx) * 32 + kb * 8;
        bf16x8 b0 = *(const bf16x8*)bp;
        bf16x8 b1 = *(const bf16x8*)(bp + 512);
        acc0 = __builtin_amdgcn_mfma_f32_16x16x32_bf16(a, b0, acc0, 0, 0, 0);
        acc1 = __builtin_amdgcn_mfma_f32_16x16x32_bf16(a, b1, acc1, 0, 0, 0);
    }
    #pragma unroll
    for (int jj = 0; jj < 2; ++jj) {
        int c = wave * 32 + jj * 16 + lx;
        float bc = bias[c];
        f32x4 av = jj ? acc1 : acc0;
        #pragma unroll
        for (int r_ = 0; r_ < 4; ++r_) {
            int n2 = nb + kb * 4 + r_;
            size_t off = (size_t)n2 * HD + c;
            float ho = av[r_] + bc + hin[off];
            hout[off] = ho;
            Ap2[n2 - nb][c] = f2bf(ho);
        }
    }
    if (nextWt == nullptr) return;
    __syncthreads();

    // ---- Epilogue: next-layer projection hout @ [W0|W1]; wave w owns 64 of 256 cols ----
    f32x4 acc[4];
    #pragma unroll
    for (int j = 0; j < 4; ++j) acc[j] = (f32x4){0.f, 0.f, 0.f, 0.f};
    for (int ks = 0; ks < 4; ++ks) {
        bf16x8 a = *(const bf16x8*)&Ap2[lx][ks * 32 + kb * 8];
        const short* bp = nextWt + (size_t)ks * 8192 + (size_t)(wave * 64 + lx) * 32 + kb * 8;
        #pragma unroll
        for (int jj = 0; jj < 4; ++jj) {
            bf16x8 bfr = *(const bf16x8*)(bp + jj * 512);
            acc[jj] = __builtin_amdgcn_mfma_f32_16x16x32_bf16(a, bfr, acc[jj], 0, 0, 0);
        }
    }
    #pragma unroll
    for (int jj = 0; jj < 4; ++jj) {
        int c = wave * 64 + jj * 16 + lx;
        #pragma unroll
        for (int r_ = 0; r_ < 4; ++r_) {
            int n2 = nb + kb * 4 + r_;
            if (c < 128) hw0n[(size_t)n2 * HD + c] = f2bf(acc[jj][r_]);
            else         hw1n[(size_t)n2 * HD + (c - 128)] = acc[jj][r_];
        }
    }
}

// Fused deterministic graph pooling + output MLP. One block per graph (batch sorted).
__global__ __launch_bounds__(256) void pool_out_kernel(
    const float* __restrict__ h, const int* __restrict__ batch,
    const float* __restrict__ W1, const float* __restrict__ b1,
    const float* __restrict__ W2, const float* __restrict__ b2,
    float* __restrict__ out)
{
    __shared__ float rs[384];
    __shared__ float red[256];
    __shared__ float s2[128], m2[128];
    int g = blockIdx.x, t = threadIdx.x;
    int lo = 0, hi = NN;
    while (lo < hi) { int mid = (lo + hi) >> 1; if (batch[mid] < g) lo = mid + 1; else hi = mid; }
    int lo2 = lo, hi2 = NN;
    while (lo2 < hi2) { int mid = (lo2 + hi2) >> 1; if (batch[mid] < g + 1) lo2 = mid + 1; else hi2 = mid; }
    int cnt = lo2 - lo;
    int f = t & 127, grp = t >> 7;
    float sum = 0.f, mx = -INFINITY;
    for (int n = lo + grp; n < lo2; n += 2) {
        float v = h[(size_t)n * HD + f];
        sum += v; mx = fmaxf(mx, v);
    }
    if (grp == 1) { s2[f] = sum; m2[f] = mx; }
    __syncthreads();
    if (grp == 0) {
        sum += s2[f]; mx = fmaxf(mx, m2[f]);
        float mean = (cnt > 0) ? sum / (float)cnt : 0.f;
        float so = (cnt > 0) ? sum : 0.f;
        float mo = (cnt > 0) ? mx : 0.f;
        if (isnan(mean) || isinf(mean)) mean = 0.f;
        if (isnan(so) || isinf(so)) so = 0.f;
        if (isnan(mo) || isinf(mo)) mo = 0.f;
        rs[f] = mean; rs[128 + f] = so; rs[256 + f] = mo;
    }
    __syncthreads();
    {
        int j = t & 127, kh = t >> 7;
        float acc = 0.f;
        for (int k = kh * 192; k < kh * 192 + 192; ++k)
            acc = fmaf(rs[k], W1[k * HD + j], acc);
        red[t] = acc;
    }
    __syncthreads();
    if (t < 128) {
        float v = fmaxf(red[t] + red[128 + t] + b1[t], 0.f);
        red[t] = v * W2[t];
    }
    __syncthreads();
    for (int s = 64; s > 0; s >>= 1) {
        if (t < s) red[t] += red[t + s];
        __syncthreads();
    }
    if (t == 0) {
        float o = red[0] + b2[0];
        if (isnan(o) || isinf(o)) o = 0.f;
        out[g] = o;
    }
}

extern "C" void kernel_launch(void* const* d_in, const int* in_sizes, int n_in,
                              void* d_out, int out_size, void* d_ws, size_t ws_size,
                              hipStream_t stream)
{
    const int* x          = (const int*)d_in[0];
    const int* ei         = (const int*)d_in[1];
    const int* ea         = (const int*)d_in[2];
    const int* batch      = (const int*)d_in[3];
    const float* atom_emb = (const float*)d_in[4];
    const float* bond_emb = (const float*)d_in[5];
    const float* pre_W    = (const float*)d_in[6];
    const float* pre_b    = (const float*)d_in[7];
    const float* post_W   = (const float*)d_in[8];
    const float* post_b   = (const float*)d_in[9];
    const float* out_W1   = (const float*)d_in[10];
    const float* out_b1   = (const float*)d_in[11];
    const float* out_W2   = (const float*)d_in[12];
    const float* out_b2   = (const float*)d_in[13];
    float* out = (float*)d_out;
    const int* row = ei;
    const int* col = ei + NE;

    char* p = (char*)d_ws;
    auto alloc = [&](size_t bytes) { char* r = p; p += (bytes + 255) & ~(size_t)255; return r; };
    float*    deg     = (float*)alloc((size_t)NN * 4);
    float*    amp     = (float*)alloc((size_t)NN * 4);
    float*    att     = (float*)alloc((size_t)NN * 4);
    int*      offsets = (int*)alloc((size_t)(NN + 1) * 4);
    int*      cursor  = (int*)alloc((size_t)NN * 4);
    int*      perm    = (int*)alloc((size_t)NE * 4);
    float*    hA      = (float*)alloc((size_t)NN * HD * 4);
    float*    hB      = (float*)alloc((size_t)NN * HD * 4);
    short*    hw0A    = (short*)alloc((size_t)NN * HD * 2);
    short*    hw0B    = (short*)alloc((size_t)NN * HD * 2);
    float*    hw1A    = (float*)alloc((size_t)NN * HD * 4);
    float*    hw1B    = (float*)alloc((size_t)NN * HD * 4);
    float*    btab    = (float*)alloc((size_t)NL * 5 * HD * 4);
    short*    pre_Wt  = (short*)alloc((size_t)NL * 4 * 256 * 32 * 2);
    short*    post_Wt = (short*)alloc((size_t)NL * 40 * 128 * 32 * 2);

    setup1_kernel<<<(NN * HD) / 256, 256, 0, stream>>>(x, atom_emb, hA, deg, cursor);
    setup2_kernel<<<645 + (NL * 40 * 128 * 32 + 255) / 256, 256, 0, stream>>>(
        col, deg, bond_emb, pre_W, pre_b, post_W, btab, pre_Wt, post_Wt);
    scan_facs_kernel<<<1, 1024, 0, stream>>>(deg, offsets, amp, att);
    scatter_kernel<<<(NE + 255) / 256, 256, 0, stream>>>(row, col, ea, offsets, cursor, perm);

    pre_gemm_mfma<<<NN / 16, 256, 0, stream>>>(hA, pre_Wt, hw0A, hw1A);

    float* curH = hA;
    float* nxtH = hB;
    for (int l = 0; l < NL; ++l) {
        short* hw0_in  = (l & 1) ? hw0B : hw0A;
        float* hw1_in  = (l & 1) ? hw1B : hw1A;
        short* hw0_out = (l & 1) ? hw0A : hw0B;
        float* hw1_out = (l & 1) ? hw1A : hw1B;
        const short* nextWt = (l + 1 < NL) ? (pre_Wt + (size_t)(l + 1) * 4 * 256 * 32) : nullptr;
        agg_node_gemm_mfma<<<NN / 16, 256, 0, stream>>>(
            hw0_in, hw1_in, btab + (size_t)l * 5 * HD, offsets, perm,
            curH, amp, att, post_Wt + (size_t)l * 40 * 128 * 32,
            post_b + (size_t)l * HD, nxtH, nextWt, hw0_out, hw1_out);
        float* tmp = curH; curH = nxtH; nxtH = tmp;
    }

    pool_out_kernel<<<NG, 256, 0, stream>>>(curH, batch, out_W1, out_b1, out_W2, out_b2, out);
}